// Round 1
// baseline (188.007 us; speedup 1.0000x reference)
//
#include <hip/hip_runtime.h>
#include <math.h>

// Problem constants (from reference)
#define N_S   256
#define C_IN  3
#define H_IN  270
#define W_IN  480
#define H_OUT 144
#define W_OUT 256
#define FEAT  32

#define GAMMA_F 1.7015043497085571f
#define FOV_RAD 0.6544984694978736f   // deg2rad(37.5)
#define SQRT_2_OVER_PI 0.7978845608028654f

__device__ __forceinline__ float gelu_gamma(float x) {
    float t = tanhf(SQRT_2_OVER_PI * (x + 0.044715f * x * x * x));
    return 0.5f * x * (1.0f + t) * GAMMA_F;
}

__global__ __launch_bounds__(256) void retina_fused_kernel(
    const float* __restrict__ stim,
    const float* __restrict__ eye,
    const float* __restrict__ W0, const float* __restrict__ b0,
    const float* __restrict__ W1, const float* __restrict__ b1,
    const float* __restrict__ Wp, const float* __restrict__ bp,
    float* __restrict__ out)
{
    __shared__ float h_s[FEAT];
    __shared__ float ang_s[3];
    __shared__ float R_s[9];

    const int blk = blockIdx.x;
    const int n   = blk / H_OUT;
    const int h   = blk - n * H_OUT;
    const int tid = threadIdx.x;   // = output w, 0..255

    // ---- per-sample MLP -> angles -> rotation matrix (redundant per block; cheap) ----
    if (tid < FEAT) {
        const float e0 = eye[n * 2 + 0];
        const float e1 = eye[n * 2 + 1];
        // W0 is [2, FEAT] row-major
        float a = fmaf(e0, W0[tid], fmaf(e1, W0[FEAT + tid], b0[tid]));
        h_s[tid] = gelu_gamma(a);
    }
    __syncthreads();
    float h1v = 0.0f;
    if (tid < FEAT) {
        float acc = b1[tid];
        #pragma unroll
        for (int k = 0; k < FEAT; ++k) acc = fmaf(h_s[k], W1[k * FEAT + tid], acc);
        h1v = gelu_gamma(acc);
    }
    __syncthreads();   // everyone done reading layer-0 h_s
    if (tid < FEAT) h_s[tid] = h1v;
    __syncthreads();
    if (tid < 3) {
        float acc = bp[tid];
        #pragma unroll
        for (int k = 0; k < FEAT; ++k) acc = fmaf(h_s[k], Wp[k * 3 + tid], acc);
        ang_s[tid] = acc;
    }
    __syncthreads();
    if (tid == 0) {
        const float cx = cosf(ang_s[0]), sx = sinf(ang_s[0]);
        const float cy = cosf(ang_s[1]), sy = sinf(ang_s[1]);
        const float cz = cosf(ang_s[2]), sz = sinf(ang_s[2]);
        // R = Rz @ Ry @ Rx
        R_s[0] = cz * cy; R_s[1] = cz * sy * sx - sz * cx; R_s[2] = cz * sy * cx + sz * sx;
        R_s[3] = sz * cy; R_s[4] = sz * sy * sx + cz * cx; R_s[5] = sz * sy * cx - cz * sx;
        R_s[6] = -sy;     R_s[7] = cy * sx;                R_s[8] = cy * cx;
    }
    __syncthreads();

    // ---- retina ray for this output pixel ----
    const float inv_s_out = 1.0f / 144.0f;                      // s = min(H_OUT, W_OUT)
    const float gx = ((tid + 0.5f) * 2.0f - (float)W_OUT) * inv_s_out;
    const float gy = ((h   + 0.5f) * 2.0f - (float)H_OUT) * inv_s_out;

    const float r     = sqrtf(gx * gx + gy * gy);
    const float theta = r * FOV_RAD;
    const float sr    = fmaxf(r, 1e-6f);
    const float st    = sinf(theta);
    const float dxv   = st * gx / sr;
    const float dyv   = st * gy / sr;
    const float dzv   = cosf(theta);

    const float rxv = R_s[0] * dxv + R_s[1] * dyv + R_s[2] * dzv;
    const float ryv = R_s[3] * dxv + R_s[4] * dyv + R_s[5] * dzv;
    const float rzv = R_s[6] * dxv + R_s[7] * dyv + R_s[8] * dzv;

    const float z  = fmaxf(rzv, 1e-6f);
    const float px = rxv / z;
    const float py = ryv / z;

    // padded-image coords: fx = px*(s_in/2) + W_IN/2 + 0.5, s_in = min(270,480) = 270
    float fx = fmaf(px, 135.0f, 240.5f);
    float fy = fmaf(py, 135.0f, 135.5f);
    // clamp to a safe range before floor/int conversion; anything out of the
    // pad ring samples zeros regardless of the (in-[0,1)) weights.
    fx = fminf(fmaxf(fx, -100.0f), 100000.0f);
    fy = fminf(fmaxf(fy, -100.0f), 100000.0f);

    const float x0f = floorf(fx), y0f = floorf(fy);
    const float wx = fx - x0f,   wy = fy - y0f;
    const int x0 = (int)x0f, y0 = (int)y0f;      // padded coords
    // unpadded image coords of the 4 taps
    const int cx0 = x0 - 1, cx1 = x0;
    const int cy0 = y0 - 1, cy1 = y0;
    const bool vx0 = (unsigned)cx0 < (unsigned)W_IN;
    const bool vx1 = (unsigned)cx1 < (unsigned)W_IN;
    const bool vy0 = (unsigned)cy0 < (unsigned)H_IN;
    const bool vy1 = (unsigned)cy1 < (unsigned)H_IN;

    const float w00 = (1.0f - wx) * (1.0f - wy);
    const float w01 = wx * (1.0f - wy);
    const float w10 = (1.0f - wx) * wy;
    const float w11 = wx * wy;

    const float* base  = stim + (size_t)n * (C_IN * H_IN * W_IN);
    float*       obase = out  + (size_t)n * (C_IN * H_OUT * W_OUT) + h * W_OUT + tid;

    #pragma unroll
    for (int c = 0; c < C_IN; ++c) {
        const float* p = base + c * (H_IN * W_IN);
        const float v00 = (vy0 && vx0) ? p[cy0 * W_IN + cx0] : 0.0f;
        const float v01 = (vy0 && vx1) ? p[cy0 * W_IN + cx1] : 0.0f;
        const float v10 = (vy1 && vx0) ? p[cy1 * W_IN + cx0] : 0.0f;
        const float v11 = (vy1 && vx1) ? p[cy1 * W_IN + cx1] : 0.0f;
        obase[c * (H_OUT * W_OUT)] = v00 * w00 + v01 * w01 + v10 * w10 + v11 * w11;
    }
}

extern "C" void kernel_launch(void* const* d_in, const int* in_sizes, int n_in,
                              void* d_out, int out_size, void* d_ws, size_t ws_size,
                              hipStream_t stream) {
    const float* stim = (const float*)d_in[0];
    const float* eye  = (const float*)d_in[1];
    const float* W0   = (const float*)d_in[2];
    const float* b0   = (const float*)d_in[3];
    const float* W1   = (const float*)d_in[4];
    const float* b1   = (const float*)d_in[5];
    const float* Wp   = (const float*)d_in[6];
    const float* bp   = (const float*)d_in[7];
    float* out = (float*)d_out;

    dim3 grid(N_S * H_OUT);
    dim3 block(W_OUT);
    retina_fused_kernel<<<grid, block, 0, stream>>>(stim, eye, W0, b0, W1, b1, Wp, bp, out);
}

// Round 2
// 170.421 us; speedup vs baseline: 1.1032x; 1.1032x over previous
//
#include <hip/hip_runtime.h>
#include <math.h>

// Problem constants (from reference)
#define N_S   256
#define C_IN  3
#define H_IN  270
#define W_IN  480
#define H_OUT 144
#define W_OUT 256
#define FEAT  32
#define HW_IN  (H_IN * W_IN)
#define HW_OUT (H_OUT * W_OUT)

#define GAMMA_F 1.7015043497085571f
#define FOV_RAD 0.6544984694978736f   // deg2rad(37.5)
#define SQRT_2_OVER_PI 0.7978845608028654f

__device__ __forceinline__ float gelu_gamma(float x) {
    float t = tanhf(SQRT_2_OVER_PI * (x + 0.044715f * x * x * x));
    return 0.5f * x * (1.0f + t) * GAMMA_F;
}

__global__ __launch_bounds__(256) void retina_fused_kernel(
    const float* __restrict__ stim,
    const float* __restrict__ eye,
    const float* __restrict__ W0, const float* __restrict__ b0,
    const float* __restrict__ W1, const float* __restrict__ b1,
    const float* __restrict__ Wp, const float* __restrict__ bp,
    float* __restrict__ out)
{
    __shared__ float h_s[FEAT];
    __shared__ float ang_s[3];
    __shared__ float R_s[9];

    // XCD-aware swizzle: dispatcher assigns block i -> XCD (i % 8).
    // Give each XCD a contiguous (n, h) range so vertically-adjacent output
    // rows (which share input tap rows) hit the same per-XCD L2.
    const int blk  = blockIdx.x;
    const int work = ((blk & 7) * (N_S * H_OUT / 8)) + (blk >> 3);
    const int n   = work / H_OUT;
    const int h   = work - n * H_OUT;
    const int tid = threadIdx.x;   // = output w, 0..255

    // ---- per-sample MLP -> angles -> rotation matrix (redundant per block; cheap) ----
    if (tid < FEAT) {
        const float e0 = eye[n * 2 + 0];
        const float e1 = eye[n * 2 + 1];
        float a = fmaf(e0, W0[tid], fmaf(e1, W0[FEAT + tid], b0[tid]));
        h_s[tid] = gelu_gamma(a);
    }
    __syncthreads();
    float h1v = 0.0f;
    if (tid < FEAT) {
        float acc = b1[tid];
        #pragma unroll
        for (int k = 0; k < FEAT; ++k) acc = fmaf(h_s[k], W1[k * FEAT + tid], acc);
        h1v = gelu_gamma(acc);
    }
    __syncthreads();
    if (tid < FEAT) h_s[tid] = h1v;
    __syncthreads();
    if (tid < 3) {
        float acc = bp[tid];
        #pragma unroll
        for (int k = 0; k < FEAT; ++k) acc = fmaf(h_s[k], Wp[k * 3 + tid], acc);
        ang_s[tid] = acc;
    }
    __syncthreads();
    if (tid == 0) {
        const float cx = cosf(ang_s[0]), sx = sinf(ang_s[0]);
        const float cy = cosf(ang_s[1]), sy = sinf(ang_s[1]);
        const float cz = cosf(ang_s[2]), sz = sinf(ang_s[2]);
        // R = Rz @ Ry @ Rx
        R_s[0] = cz * cy; R_s[1] = cz * sy * sx - sz * cx; R_s[2] = cz * sy * cx + sz * sx;
        R_s[3] = sz * cy; R_s[4] = sz * sy * sx + cz * cx; R_s[5] = sz * sy * cx - cz * sx;
        R_s[6] = -sy;     R_s[7] = cy * sx;                R_s[8] = cy * cx;
    }
    __syncthreads();

    // ---- retina ray for this output pixel ----
    const float inv_s_out = 1.0f / 144.0f;                      // s = min(H_OUT, W_OUT)
    const float gx = ((tid + 0.5f) * 2.0f - (float)W_OUT) * inv_s_out;
    const float gy = ((h   + 0.5f) * 2.0f - (float)H_OUT) * inv_s_out;

    const float r     = sqrtf(gx * gx + gy * gy);
    const float theta = r * FOV_RAD;
    const float sr    = fmaxf(r, 1e-6f);
    const float st    = sinf(theta);
    const float dxv   = st * gx / sr;
    const float dyv   = st * gy / sr;
    const float dzv   = cosf(theta);

    const float rxv = R_s[0] * dxv + R_s[1] * dyv + R_s[2] * dzv;
    const float ryv = R_s[3] * dxv + R_s[4] * dyv + R_s[5] * dzv;
    const float rzv = R_s[6] * dxv + R_s[7] * dyv + R_s[8] * dzv;

    const float z  = fmaxf(rzv, 1e-6f);
    const float px = rxv / z;
    const float py = ryv / z;

    // padded-image coords: fx = px*(s_in/2) + W_IN/2 + 0.5, s_in = min(270,480) = 270
    float fx = fmaf(px, 135.0f, 240.5f);
    float fy = fmaf(py, 135.0f, 135.5f);
    fx = fminf(fmaxf(fx, -100.0f), 100000.0f);
    fy = fminf(fmaxf(fy, -100.0f), 100000.0f);

    const float x0f = floorf(fx), y0f = floorf(fy);
    const float wx = fx - x0f,   wy = fy - y0f;
    const int x0 = (int)x0f, y0 = (int)y0f;      // padded coords
    // unpadded image coords of the 4 taps
    const int cx0 = x0 - 1, cx1 = x0;
    const int cy0 = y0 - 1, cy1 = y0;
    const bool vx0 = (unsigned)cx0 < (unsigned)W_IN;
    const bool vx1 = (unsigned)cx1 < (unsigned)W_IN;
    const bool vy0 = (unsigned)cy0 < (unsigned)H_IN;
    const bool vy1 = (unsigned)cy1 < (unsigned)H_IN;

    float r0 = 0.0f, r1 = 0.0f, r2 = 0.0f;

    if ((vx0 || vx1) && (vy0 || vy1)) {
        // Fold tap validity into the bilinear weights (identical to the
        // zero-pad ring), clamp indices so every load is in-bounds, and
        // issue all 12 gathers back-to-back with no exec-mask juggling.
        const float wxa = (1.0f - wx) * (vx0 ? 1.0f : 0.0f);
        const float wxb = wx          * (vx1 ? 1.0f : 0.0f);
        const float wya = (1.0f - wy) * (vy0 ? 1.0f : 0.0f);
        const float wyb = wy          * (vy1 ? 1.0f : 0.0f);
        const float w00 = wxa * wya, w01 = wxb * wya;
        const float w10 = wxa * wyb, w11 = wxb * wyb;

        const int cx0c = min(max(cx0, 0), W_IN - 1);
        const int cx1c = min(max(cx1, 0), W_IN - 1);
        const int cy0c = min(max(cy0, 0), H_IN - 1);
        const int cy1c = min(max(cy1, 0), H_IN - 1);

        const unsigned o00 = (unsigned)(cy0c * W_IN + cx0c);
        const unsigned o01 = (unsigned)(cy0c * W_IN + cx1c);
        const unsigned o10 = (unsigned)(cy1c * W_IN + cx0c);
        const unsigned o11 = (unsigned)(cy1c * W_IN + cx1c);

        const float* __restrict__ p0 = stim + (size_t)n * (C_IN * HW_IN);
        const float* __restrict__ p1 = p0 + HW_IN;
        const float* __restrict__ p2 = p0 + 2 * HW_IN;

        const float a00 = p0[o00], a01 = p0[o01], a10 = p0[o10], a11 = p0[o11];
        const float b00 = p1[o00], b01 = p1[o01], b10 = p1[o10], b11 = p1[o11];
        const float c00 = p2[o00], c01 = p2[o01], c10 = p2[o10], c11 = p2[o11];

        r0 = fmaf(a00, w00, fmaf(a01, w01, fmaf(a10, w10, a11 * w11)));
        r1 = fmaf(b00, w00, fmaf(b01, w01, fmaf(b10, w10, b11 * w11)));
        r2 = fmaf(c00, w00, fmaf(c01, w01, fmaf(c10, w10, c11 * w11)));
    }

    float* op = out + (size_t)n * (C_IN * HW_OUT) + h * W_OUT + tid;
    __builtin_nontemporal_store(r0, op);
    __builtin_nontemporal_store(r1, op + HW_OUT);
    __builtin_nontemporal_store(r2, op + 2 * HW_OUT);
}

extern "C" void kernel_launch(void* const* d_in, const int* in_sizes, int n_in,
                              void* d_out, int out_size, void* d_ws, size_t ws_size,
                              hipStream_t stream) {
    const float* stim = (const float*)d_in[0];
    const float* eye  = (const float*)d_in[1];
    const float* W0   = (const float*)d_in[2];
    const float* b0   = (const float*)d_in[3];
    const float* W1   = (const float*)d_in[4];
    const float* b1   = (const float*)d_in[5];
    const float* Wp   = (const float*)d_in[6];
    const float* bp   = (const float*)d_in[7];
    float* out = (float*)d_out;

    dim3 grid(N_S * H_OUT);
    dim3 block(W_OUT);
    retina_fused_kernel<<<grid, block, 0, stream>>>(stim, eye, W0, b0, W1, b1, Wp, bp, out);
}

// Round 3
// 152.868 us; speedup vs baseline: 1.2299x; 1.1148x over previous
//
#include <hip/hip_runtime.h>
#include <math.h>

// Problem constants (from reference)
#define N_S   256
#define C_IN  3
#define H_IN  270
#define W_IN  480
#define H_OUT 144
#define W_OUT 256
#define FEAT  32
#define HW_IN  (H_IN * W_IN)
#define HW_OUT (H_OUT * W_OUT)

#define GAMMA_F 1.7015043497085571f
#define FOV_RAD 0.6544984694978736f   // deg2rad(37.5)
#define SQRT_2_OVER_PI 0.7978845608028654f

// ws layout
#define WS_R_OFF  0        // 256 * 9 floats
#define WS_D_OFF  16384    // byte offset; 36864 float4

__device__ __forceinline__ float gelu_gamma(float x) {
    float t = tanhf(SQRT_2_OVER_PI * (x + 0.044715f * x * x * x));
    return 0.5f * x * (1.0f + t) * GAMMA_F;
}

// ---------------- Kernel A: per-sample MLP -> rotation matrix ----------------
__global__ __launch_bounds__(64) void mlp_rot_kernel(
    const float* __restrict__ eye,
    const float* __restrict__ W0, const float* __restrict__ b0,
    const float* __restrict__ W1, const float* __restrict__ b1,
    const float* __restrict__ Wp, const float* __restrict__ bp,
    float* __restrict__ wsR)
{
    __shared__ float h_s[FEAT];
    __shared__ float ang_s[3];
    __shared__ float R_s[9];
    const int n   = blockIdx.x;
    const int tid = threadIdx.x;

    if (tid < FEAT) {
        const float e0 = eye[n * 2 + 0];
        const float e1 = eye[n * 2 + 1];
        float a = fmaf(e0, W0[tid], fmaf(e1, W0[FEAT + tid], b0[tid]));
        h_s[tid] = gelu_gamma(a);
    }
    __syncthreads();
    float h1v = 0.0f;
    if (tid < FEAT) {
        float acc = b1[tid];
        #pragma unroll
        for (int k = 0; k < FEAT; ++k) acc = fmaf(h_s[k], W1[k * FEAT + tid], acc);
        h1v = gelu_gamma(acc);
    }
    __syncthreads();
    if (tid < FEAT) h_s[tid] = h1v;
    __syncthreads();
    if (tid < 3) {
        float acc = bp[tid];
        #pragma unroll
        for (int k = 0; k < FEAT; ++k) acc = fmaf(h_s[k], Wp[k * 3 + tid], acc);
        ang_s[tid] = acc;
    }
    __syncthreads();
    if (tid == 0) {
        const float cx = cosf(ang_s[0]), sx = sinf(ang_s[0]);
        const float cy = cosf(ang_s[1]), sy = sinf(ang_s[1]);
        const float cz = cosf(ang_s[2]), sz = sinf(ang_s[2]);
        R_s[0] = cz * cy; R_s[1] = cz * sy * sx - sz * cx; R_s[2] = cz * sy * cx + sz * sx;
        R_s[3] = sz * cy; R_s[4] = sz * sy * sx + cz * cx; R_s[5] = sz * sy * cx - cz * sx;
        R_s[6] = -sy;     R_s[7] = cy * sx;                R_s[8] = cy * cx;
    }
    __syncthreads();
    if (tid < 9) wsR[n * 9 + tid] = R_s[tid];
}

// ---------------- Kernel B: per-pixel retina ray direction table -------------
__global__ __launch_bounds__(256) void ray_table_kernel(float4* __restrict__ wsD)
{
    const int i = blockIdx.x * 256 + threadIdx.x;   // 0 .. 36863
    const int h = i >> 8;
    const int w = i & 255;

    const float inv_s = 1.0f / 144.0f;
    const float gx = ((w + 0.5f) * 2.0f - (float)W_OUT) * inv_s;
    const float gy = ((h + 0.5f) * 2.0f - (float)H_OUT) * inv_s;

    const float r     = sqrtf(gx * gx + gy * gy);
    const float theta = r * FOV_RAD;
    const float sr    = fmaxf(r, 1e-6f);
    const float st    = sinf(theta);
    float4 d;
    d.x = st * gx / sr;
    d.y = st * gy / sr;
    d.z = cosf(theta);
    d.w = 0.0f;
    wsD[i] = d;
}

// ---------------- Kernel C: hot gather kernel --------------------------------
// 8-byte tap-pair load; only 4-byte alignment is guaranteed.
struct __attribute__((packed, aligned(4))) f2a { float x, y; };

__global__ __launch_bounds__(256) void retina_sample_kernel(
    const float* __restrict__ stim,
    const float* __restrict__ wsR,
    const float4* __restrict__ wsD,
    float* __restrict__ out)
{
    // XCD-aware swizzle (bijective: 36864 % 8 == 0)
    const int blk  = blockIdx.x;
    const int work = ((blk & 7) * (N_S * H_OUT / 8)) + (blk >> 3);
    const int n   = work / H_OUT;
    const int h   = work - n * H_OUT;
    const int tid = threadIdx.x;   // = output w

    // rotation matrix: n is wave-uniform -> scalar loads
    float Rm[9];
    #pragma unroll
    for (int i = 0; i < 9; ++i) Rm[i] = wsR[n * 9 + i];

    const float4 d = wsD[h * W_OUT + tid];

    const float rxv = fmaf(Rm[0], d.x, fmaf(Rm[1], d.y, Rm[2] * d.z));
    const float ryv = fmaf(Rm[3], d.x, fmaf(Rm[4], d.y, Rm[5] * d.z));
    const float rzv = fmaf(Rm[6], d.x, fmaf(Rm[7], d.y, Rm[8] * d.z));

    const float z     = fmaxf(rzv, 1e-6f);
    const float inv_z = __builtin_amdgcn_rcpf(z);
    const float px = rxv * inv_z;
    const float py = ryv * inv_z;

    float fx = fmaf(px, 135.0f, 240.5f);
    float fy = fmaf(py, 135.0f, 135.5f);
    fx = fminf(fmaxf(fx, -100.0f), 100000.0f);
    fy = fminf(fmaxf(fy, -100.0f), 100000.0f);

    const float x0f = floorf(fx), y0f = floorf(fy);
    const float wx = fx - x0f,   wy = fy - y0f;
    const int x0 = (int)x0f, y0 = (int)y0f;      // padded coords
    const int cx0 = x0 - 1, cx1 = x0;            // unpadded tap columns
    const int cy0 = y0 - 1, cy1 = y0;            // unpadded tap rows

    // validity-folded weights (identical to the zero-pad ring)
    const float wxa = ((unsigned)cx0 < (unsigned)W_IN) ? (1.0f - wx) : 0.0f;
    const float wxb = ((unsigned)cx1 < (unsigned)W_IN) ? wx          : 0.0f;
    const float wya = ((unsigned)cy0 < (unsigned)H_IN) ? (1.0f - wy) : 0.0f;
    const float wyb = ((unsigned)cy1 < (unsigned)H_IN) ? wy          : 0.0f;

    // remap horizontal taps onto the clamped 2-wide window [b, b+1]
    const int b = min(max(cx0, 0), W_IN - 2);
    const float wl = (cx0 == b) ? wxa : ((cx0 == b - 1) ? wxb : 0.0f);
    const float wr = (cx0 == b) ? wxb : ((cx0 == b + 1) ? wxa : 0.0f);
    // remap vertical taps onto clamped rows [yb, yb+1]
    const int yb = min(max(cy0, 0), H_IN - 2);
    const float wt = (cy0 == yb) ? wya : ((cy0 == yb - 1) ? wyb : 0.0f);
    const float wb = (cy0 == yb) ? wyb : ((cy0 == yb + 1) ? wya : 0.0f);

    const float c00 = wt * wl, c01 = wt * wr;
    const float c10 = wb * wl, c11 = wb * wr;

    const float* __restrict__ p0 = stim + (size_t)n * (C_IN * HW_IN) + yb * W_IN + b;
    const float* __restrict__ q0 = p0 + W_IN;

    const f2a a0 = *reinterpret_cast<const f2a*>(p0);
    const f2a a1 = *reinterpret_cast<const f2a*>(q0);
    const f2a b0 = *reinterpret_cast<const f2a*>(p0 + HW_IN);
    const f2a b1 = *reinterpret_cast<const f2a*>(q0 + HW_IN);
    const f2a c0 = *reinterpret_cast<const f2a*>(p0 + 2 * HW_IN);
    const f2a c1 = *reinterpret_cast<const f2a*>(q0 + 2 * HW_IN);

    const float r0 = fmaf(a0.x, c00, fmaf(a0.y, c01, fmaf(a1.x, c10, a1.y * c11)));
    const float r1 = fmaf(b0.x, c00, fmaf(b0.y, c01, fmaf(b1.x, c10, b1.y * c11)));
    const float r2 = fmaf(c0.x, c00, fmaf(c0.y, c01, fmaf(c1.x, c10, c1.y * c11)));

    float* op = out + (size_t)n * (C_IN * HW_OUT) + h * W_OUT + tid;
    __builtin_nontemporal_store(r0, op);
    __builtin_nontemporal_store(r1, op + HW_OUT);
    __builtin_nontemporal_store(r2, op + 2 * HW_OUT);
}

extern "C" void kernel_launch(void* const* d_in, const int* in_sizes, int n_in,
                              void* d_out, int out_size, void* d_ws, size_t ws_size,
                              hipStream_t stream) {
    const float* stim = (const float*)d_in[0];
    const float* eye  = (const float*)d_in[1];
    const float* W0   = (const float*)d_in[2];
    const float* b0   = (const float*)d_in[3];
    const float* W1   = (const float*)d_in[4];
    const float* b1   = (const float*)d_in[5];
    const float* Wp   = (const float*)d_in[6];
    const float* bp   = (const float*)d_in[7];
    float* out = (float*)d_out;

    float*  wsR = (float*)((char*)d_ws + WS_R_OFF);
    float4* wsD = (float4*)((char*)d_ws + WS_D_OFF);

    mlp_rot_kernel<<<dim3(N_S), dim3(64), 0, stream>>>(eye, W0, b0, W1, b1, Wp, bp, wsR);
    ray_table_kernel<<<dim3(HW_OUT / 256), dim3(256), 0, stream>>>(wsD);
    retina_sample_kernel<<<dim3(N_S * H_OUT), dim3(256), 0, stream>>>(stim, wsR, wsD, out);
}

// Round 4
// 135.180 us; speedup vs baseline: 1.3908x; 1.1309x over previous
//
#include <hip/hip_runtime.h>
#include <math.h>

// Problem constants (from reference)
#define N_S   256
#define C_IN  3
#define H_IN  270
#define W_IN  480
#define H_OUT 144
#define W_OUT 256
#define FEAT  32
#define HW_IN  (H_IN * W_IN)
#define HW_OUT (H_OUT * W_OUT)

#define GAMMA_F 1.7015043497085571f
#define FOV_RAD 0.6544984694978736f   // deg2rad(37.5)
#define SQRT_2_OVER_PI 0.7978845608028654f

#define WS_R_OFF  0        // 256 * 9 floats

__device__ __forceinline__ float gelu_gamma(float x) {
    float t = tanhf(SQRT_2_OVER_PI * (x + 0.044715f * x * x * x));
    return 0.5f * x * (1.0f + t) * GAMMA_F;
}

// ---------------- Kernel A: per-sample MLP -> rotation matrix ----------------
__global__ __launch_bounds__(64) void mlp_rot_kernel(
    const float* __restrict__ eye,
    const float* __restrict__ W0, const float* __restrict__ b0,
    const float* __restrict__ W1, const float* __restrict__ b1,
    const float* __restrict__ Wp, const float* __restrict__ bp,
    float* __restrict__ wsR)
{
    __shared__ float h_s[FEAT];
    __shared__ float ang_s[3];
    __shared__ float R_s[9];
    const int n   = blockIdx.x;
    const int tid = threadIdx.x;

    if (tid < FEAT) {
        const float e0 = eye[n * 2 + 0];
        const float e1 = eye[n * 2 + 1];
        float a = fmaf(e0, W0[tid], fmaf(e1, W0[FEAT + tid], b0[tid]));
        h_s[tid] = gelu_gamma(a);
    }
    __syncthreads();
    float h1v = 0.0f;
    if (tid < FEAT) {
        float acc = b1[tid];
        #pragma unroll
        for (int k = 0; k < FEAT; ++k) acc = fmaf(h_s[k], W1[k * FEAT + tid], acc);
        h1v = gelu_gamma(acc);
    }
    __syncthreads();
    if (tid < FEAT) h_s[tid] = h1v;
    __syncthreads();
    if (tid < 3) {
        float acc = bp[tid];
        #pragma unroll
        for (int k = 0; k < FEAT; ++k) acc = fmaf(h_s[k], Wp[k * 3 + tid], acc);
        ang_s[tid] = acc;
    }
    __syncthreads();
    if (tid == 0) {
        const float cx = cosf(ang_s[0]), sx = sinf(ang_s[0]);
        const float cy = cosf(ang_s[1]), sy = sinf(ang_s[1]);
        const float cz = cosf(ang_s[2]), sz = sinf(ang_s[2]);
        R_s[0] = cz * cy; R_s[1] = cz * sy * sx - sz * cx; R_s[2] = cz * sy * cx + sz * sx;
        R_s[3] = sz * cy; R_s[4] = sz * sy * sx + cz * cx; R_s[5] = sz * sy * cx - cz * sx;
        R_s[6] = -sy;     R_s[7] = cy * sx;                R_s[8] = cy * cx;
    }
    __syncthreads();
    if (tid < 9) wsR[n * 9 + tid] = R_s[tid];
}

// ---------------- Kernel C: hot gather kernel --------------------------------
// 8-byte tap-pair load; only 4-byte alignment is guaranteed.
struct __attribute__((packed, aligned(4))) f2a { float x, y; };

// grid: 18432 blocks = 256 samples x 72 row-pairs; each thread does 2 rows.
__global__ __launch_bounds__(256) void retina_sample_kernel(
    const float* __restrict__ stim,
    const float* __restrict__ wsR,
    float* __restrict__ out)
{
    // XCD-aware swizzle (bijective: 18432 % 8 == 0)
    const int blk  = blockIdx.x;
    const int work = ((blk & 7) * (18432 / 8)) + (blk >> 3);
    const int n   = work / (H_OUT / 2);
    const int hp  = work - n * (H_OUT / 2);
    const int tid = threadIdx.x;   // = output w

    // rotation matrix: n is block-uniform -> scalar loads
    float Rm[9];
    #pragma unroll
    for (int i = 0; i < 9; ++i) Rm[i] = wsR[n * 9 + i];

    const float gx  = ((tid + 0.5f) * 2.0f - (float)W_OUT) * (1.0f / 144.0f);
    const float gx2 = gx * gx;

    const float* __restrict__ sbase = stim + (size_t)n * (C_IN * HW_IN);
    float* __restrict__ obase = out + (size_t)n * (C_IN * HW_OUT) + tid;

    #pragma unroll
    for (int rr = 0; rr < 2; ++rr) {
        const int   h  = 2 * hp + rr;
        const float gy = ((h + 0.5f) * 2.0f - (float)H_OUT) * (1.0f / 144.0f);
        const float u  = fmaf(gy, gy, gx2);                 // r^2
        const float x  = u * (FOV_RAD * FOV_RAD);           // (k*r)^2 <= ~1.77

        // sin(k*r)/r = k * P(x), cos(k*r) = Q(x); Taylor, trunc err < 1e-8
        const float sinp = 1.0f + x * (-1.6666667e-1f + x * (8.3333333e-3f
                         + x * (-1.9841270e-4f + x * (2.7557319e-6f
                         + x * (-2.5052108e-8f)))));
        const float cosp = 1.0f + x * (-0.5f + x * (4.1666667e-2f
                         + x * (-1.3888889e-3f + x * (2.4801587e-5f
                         + x * (-2.7557319e-7f + x * 2.0876757e-9f)))));

        const float S   = FOV_RAD * sinp;                   // sin(theta)/r
        const float dxv = S * gx;
        const float dyv = S * gy;
        const float dzv = cosp;

        const float rxv = fmaf(Rm[0], dxv, fmaf(Rm[1], dyv, Rm[2] * dzv));
        const float ryv = fmaf(Rm[3], dxv, fmaf(Rm[4], dyv, Rm[5] * dzv));
        const float rzv = fmaf(Rm[6], dxv, fmaf(Rm[7], dyv, Rm[8] * dzv));

        const float z     = fmaxf(rzv, 1e-6f);
        const float inv_z = __builtin_amdgcn_rcpf(z);
        const float px = rxv * inv_z;
        const float py = ryv * inv_z;

        float fx = fmaf(px, 135.0f, 240.5f);
        float fy = fmaf(py, 135.0f, 135.5f);
        fx = fminf(fmaxf(fx, -100.0f), 100000.0f);
        fy = fminf(fmaxf(fy, -100.0f), 100000.0f);

        const float x0f = floorf(fx), y0f = floorf(fy);
        const float wx = fx - x0f,   wy = fy - y0f;
        const int x0 = (int)x0f, y0 = (int)y0f;      // padded coords
        const int cx0 = x0 - 1;                      // unpadded tap col/row
        const int cy0 = y0 - 1;

        // validity-folded weights (identical to the zero-pad ring)
        const float wxa = ((unsigned)cx0       < (unsigned)W_IN) ? (1.0f - wx) : 0.0f;
        const float wxb = ((unsigned)(cx0 + 1) < (unsigned)W_IN) ? wx          : 0.0f;
        const float wya = ((unsigned)cy0       < (unsigned)H_IN) ? (1.0f - wy) : 0.0f;
        const float wyb = ((unsigned)(cy0 + 1) < (unsigned)H_IN) ? wy          : 0.0f;

        // remap taps onto the clamped 2-wide windows [b,b+1] x [yb,yb+1]
        const int b = min(max(cx0, 0), W_IN - 2);
        const float wl = (cx0 == b) ? wxa : ((cx0 == b - 1) ? wxb : 0.0f);
        const float wr = (cx0 == b) ? wxb : ((cx0 == b + 1) ? wxa : 0.0f);
        const int yb = min(max(cy0, 0), H_IN - 2);
        const float wt = (cy0 == yb) ? wya : ((cy0 == yb - 1) ? wyb : 0.0f);
        const float wb = (cy0 == yb) ? wyb : ((cy0 == yb + 1) ? wya : 0.0f);

        const float c00 = wt * wl, c01 = wt * wr;
        const float c10 = wb * wl, c11 = wb * wr;

        const float* __restrict__ p0 = sbase + yb * W_IN + b;
        const float* __restrict__ q0 = p0 + W_IN;

        const f2a a0 = *reinterpret_cast<const f2a*>(p0);
        const f2a a1 = *reinterpret_cast<const f2a*>(q0);
        const f2a b0 = *reinterpret_cast<const f2a*>(p0 + HW_IN);
        const f2a b1 = *reinterpret_cast<const f2a*>(q0 + HW_IN);
        const f2a c0 = *reinterpret_cast<const f2a*>(p0 + 2 * HW_IN);
        const f2a c1 = *reinterpret_cast<const f2a*>(q0 + 2 * HW_IN);

        const float r0 = fmaf(a0.x, c00, fmaf(a0.y, c01, fmaf(a1.x, c10, a1.y * c11)));
        const float r1 = fmaf(b0.x, c00, fmaf(b0.y, c01, fmaf(b1.x, c10, b1.y * c11)));
        const float r2 = fmaf(c0.x, c00, fmaf(c0.y, c01, fmaf(c1.x, c10, c1.y * c11)));

        float* op = obase + h * W_OUT;
        __builtin_nontemporal_store(r0, op);
        __builtin_nontemporal_store(r1, op + HW_OUT);
        __builtin_nontemporal_store(r2, op + 2 * HW_OUT);
    }
}

extern "C" void kernel_launch(void* const* d_in, const int* in_sizes, int n_in,
                              void* d_out, int out_size, void* d_ws, size_t ws_size,
                              hipStream_t stream) {
    const float* stim = (const float*)d_in[0];
    const float* eye  = (const float*)d_in[1];
    const float* W0   = (const float*)d_in[2];
    const float* b0   = (const float*)d_in[3];
    const float* W1   = (const float*)d_in[4];
    const float* b1   = (const float*)d_in[5];
    const float* Wp   = (const float*)d_in[6];
    const float* bp   = (const float*)d_in[7];
    float* out = (float*)d_out;

    float* wsR = (float*)((char*)d_ws + WS_R_OFF);

    mlp_rot_kernel<<<dim3(N_S), dim3(64), 0, stream>>>(eye, W0, b0, W1, b1, Wp, bp, wsR);
    retina_sample_kernel<<<dim3(N_S * H_OUT / 2), dim3(256), 0, stream>>>(stim, wsR, out);
}